// Round 2
// baseline (388.438 us; speedup 1.0000x reference)
//
#include <hip/hip_runtime.h>
#include <hip/hip_bf16.h>

typedef __attribute__((ext_vector_type(8))) short short8;
typedef __attribute__((ext_vector_type(4))) float f32x4;

__device__ inline f32x4 mfma16(short8 a, short8 b, f32x4 c) {
    return __builtin_amdgcn_mfma_f32_16x16x32_bf16(a, b, c, 0, 0, 0);
}
__device__ inline short f2bf(float x) {
    __hip_bfloat16 h = __float2bfloat16(x);
    return *reinterpret_cast<short*>(&h);
}
__device__ inline unsigned short f2bfu(float x) {
    __hip_bfloat16 h = __float2bfloat16(x);
    return *reinterpret_cast<unsigned short*>(&h);
}
__device__ inline float bf2f(short u) {
    __hip_bfloat16 h = *reinterpret_cast<__hip_bfloat16*>(&u);
    return __bfloat162float(h);
}
__device__ inline float scrub(float v, float s) {
    return (fabsf(v) < 1e30f) ? v : s;
}
__device__ inline short8 scaleq(short8 v) {   // fold 1/sqrt(hd)=0.125 into Q (exact in bf16)
    short8 r;
#pragma unroll
    for (int j = 0; j < 8; j++) r[j] = f2bf(bf2f(v[j]) * 0.125f);
    return r;
}

// ---- dtype detection ----
__global__ void detect_dtype(const unsigned short* __restrict__ x, int* flag) {
    __shared__ int cnt;
    if (threadIdx.x == 0) cnt = 0;
    __syncthreads();
    int c = 0;
    for (int i = threadIdx.x; i < 1024; i += 256) {
        unsigned short u = x[i];
        int e = (u >> 7) & 0xFF;
        if ((u & 0x7FFF) == 0 || (e >= 110 && e <= 143)) c++;
    }
    atomicAdd(&cnt, c);
    __syncthreads();
    if (threadIdx.x == 0) flag[0] = (cnt < 819) ? 1 : 0;
}

__global__ void conv_bias(const void* __restrict__ in, short* __restrict__ out,
                          int n, const int* __restrict__ flag) {
    int i = blockIdx.x * 256 + threadIdx.x;
    if (i >= n) return;
    out[i] = (*flag) ? f2bf(((const float*)in)[i]) : ((const short*)in)[i];
}

__global__ __launch_bounds__(256) void conv_x(const void* __restrict__ in,
                                              short* __restrict__ out, int n,
                                              const int* __restrict__ flag) {
    int i = (blockIdx.x * 256 + threadIdx.x) * 4;
    if (i >= n) return;
    if (*flag) {
        float4 f = *(const float4*)((const float*)in + i);
        unsigned int u0 = ((unsigned int)f2bfu(f.y) << 16) | f2bfu(f.x);
        unsigned int u1 = ((unsigned int)f2bfu(f.w) << 16) | f2bfu(f.z);
        *(uint2*)(out + i) = make_uint2(u0, u1);
    } else {
        *(uint2*)(out + i) = *(const uint2*)((const short*)in + i);
    }
}

__global__ void fill_sentinel(void* out, int n, const int* __restrict__ flag) {
    int i = blockIdx.x * 256 + threadIdx.x;
    if (i >= n) return;
    if (*flag) ((float*)out)[i] = 3e5f; else ((short*)out)[i] = f2bf(3e5f);
}

// ---- transpose (poly input) ----
__global__ __launch_bounds__(256) void transpose_poly(const void* __restrict__ in,
                                                      short* __restrict__ out,
                                                      int R, int C,
                                                      const int* __restrict__ flag) {
    __shared__ short tile[32][33];
    const bool f32 = (*flag) != 0;
    int tx = threadIdx.x & 31, ty = threadIdx.x >> 5;
    int r0 = blockIdx.y * 32, c0 = blockIdx.x * 32;
#pragma unroll
    for (int i = 0; i < 4; i++) {
        size_t off = (size_t)(r0 + ty + i * 8) * C + c0 + tx;
        tile[ty + i * 8][tx] = f32 ? f2bf(((const float*)in)[off]) : ((const short*)in)[off];
    }
    __syncthreads();
#pragma unroll
    for (int i = 0; i < 4; i++)
        out[(size_t)(c0 + ty + i * 8) * R + r0 + tx] = tile[tx][ty + i * 8];
}

// ---- GEMM (unchanged) ----
#define LDK 72

__global__ __launch_bounds__(256) void gemm_bt(const short* __restrict__ A,
                                               const short* __restrict__ Bt,
                                               const short* __restrict__ bias,
                                               void* __restrict__ Cv,
                                               int N, int K,
                                               const int* __restrict__ flag,
                                               int c_poly, float sent) {
    alignas(16) __shared__ short As[128 * LDK];
    alignas(16) __shared__ short Bs[128 * LDK];
    const bool cf32 = c_poly && (*flag);
    int tid = threadIdx.x;
    int wave = tid >> 6, lane = tid & 63;
    int lrow = lane & 15, lq = lane >> 4;
    int wm = (wave >> 1) * 64, wn = (wave & 1) * 64;
    int m0 = blockIdx.y * 128, n0 = blockIdx.x * 128;

    f32x4 acc[4][4];
#pragma unroll
    for (int i = 0; i < 4; i++)
#pragma unroll
        for (int j = 0; j < 4; j++) acc[i][j] = (f32x4){0.f, 0.f, 0.f, 0.f};

    int srow = tid >> 3;
    int scol = (tid & 7) * 8;

    for (int kb = 0; kb < K; kb += 64) {
#pragma unroll
        for (int p = 0; p < 4; p++) {
            int row = p * 32 + srow;
            *(short8*)&As[row * LDK + scol] =
                *(const short8*)&A[(size_t)(m0 + row) * K + kb + scol];
            *(short8*)&Bs[row * LDK + scol] =
                *(const short8*)&Bt[(size_t)(n0 + row) * K + kb + scol];
        }
        __syncthreads();
#pragma unroll
        for (int ks = 0; ks < 2; ks++) {
            short8 af[4], bf[4];
#pragma unroll
            for (int i = 0; i < 4; i++)
                af[i] = *(short8*)&As[(wm + i * 16 + lrow) * LDK + ks * 32 + lq * 8];
#pragma unroll
            for (int i = 0; i < 4; i++)
                bf[i] = *(short8*)&Bs[(wn + i * 16 + lrow) * LDK + ks * 32 + lq * 8];
#pragma unroll
            for (int i = 0; i < 4; i++)
#pragma unroll
                for (int j = 0; j < 4; j++)
                    acc[i][j] = mfma16(af[i], bf[j], acc[i][j]);
        }
        __syncthreads();
    }

    const __hip_bfloat16* bias16 = (const __hip_bfloat16*)bias;
#pragma unroll
    for (int j = 0; j < 4; j++) {
        int col = n0 + wn + j * 16 + lrow;
        float bv = __bfloat162float(bias16[col]);
#pragma unroll
        for (int i = 0; i < 4; i++) {
            int rbase = m0 + wm + i * 16 + lq * 4;
#pragma unroll
            for (int r = 0; r < 4; r++) {
                float val = scrub(acc[i][j][r] + bv, sent);
                size_t off = (size_t)(rbase + r) * N + col;
                if (cf32) ((float*)Cv)[off] = val; else ((short*)Cv)[off] = f2bf(val);
            }
        }
    }
}

// ---- flash attention, S^T formulation, 128 q / block, kv-split x2 ----------
// Block = 512 threads (8 waves). Waves 0-3 (kv-group 0) and 4-7 (kv-group 1)
// own the SAME 128 q rows but alternate 64-kv iterations: group g processes
// kv0 = kv0g + g*64, kv0g += 128. Both tile kv-counts are multiples of 128 ->
// identical trip counts, uniform barriers. Private (m,l,acc) per group; LDS
// merge at tile end. Doubles waves/CU (8 -> 16) vs the 256-thread version.
// Single smem[] array: merge overlay at base is provably in-bounds
// (37,888 B <= 73,728 B) -- round-1's &Vt[0] overlay relied on LDS layout
// order and could go OOB.
// Numerics: exact *0.125 Q scale, __expf, defer-max (skip acc rescale while
// all rows' max grew <= 8; p <= e^8 fits bf16; frozen-max garbage for fully
// masked rows is flushed by alpha=0 / eb=0 at merge).
#define VP2 72
#define PP 72
#define VT_ELEMS (2 * 2 * 64 * VP2)   // 18432 shorts = 36864 B
#define PT_ELEMS (8 * 2 * 16 * PP)    // 18432 shorts = 36864 B

__global__ __launch_bounds__(512, 4) void attn_kernel(const short* __restrict__ QKV,
                                                      short* __restrict__ AO,
                                                      const int* __restrict__ maskp) {
    constexpr int S = 2048, C3 = 3072;
    alignas(16) __shared__ short smem[VT_ELEMS + PT_ELEMS];

    int tid = threadIdx.x;
    int wave = tid >> 6, lane = tid & 63;
    int wq = wave & 3, gsel = wave >> 2;
    int lrow = lane & 15, lq = lane >> 4;
    int bh = blockIdx.y;
    const bool causal = (*maskp) != 0;
    const short* base = QKV + (size_t)(bh >> 4) * S * C3 + (bh & 15) * 192;

    int t8 = tid & 255;               // index within kv-group's 256 threads
    int vi2 = (t8 & 31) * 2;          // kv pair base for V staging
    int vd0 = (t8 >> 5) * 8;          // 8 d per thread

    short* PtA = smem + VT_ELEMS + (wave * 2 + 0) * 16 * PP;
    short* PtB = smem + VT_ELEMS + (wave * 2 + 1) * 16 * PP;

    int buf = 0;
    for (int tile = 0; tile < 2; tile++) {
        int q0t = (tile == 0) ? blockIdx.x * 128 : 1920 - blockIdx.x * 128;

        int qg[2];
        short8 qf0[2], qf1[2];
#pragma unroll
        for (int g = 0; g < 2; g++) {
            qg[g] = q0t + wq * 32 + g * 16 + lrow;
            qf0[g] = scaleq(*(const short8*)(base + (size_t)qg[g] * C3 + lq * 8));
            qf1[g] = scaleq(*(const short8*)(base + (size_t)qg[g] * C3 + 32 + lq * 8));
        }

        float m_i[2] = {-1e38f, -1e38f}, l_i[2] = {0.f, 0.f};
        f32x4 acc[2][4];
#pragma unroll
        for (int g = 0; g < 2; g++)
#pragma unroll
            for (int nt = 0; nt < 4; nt++) acc[g][nt] = (f32x4){0.f, 0.f, 0.f, 0.f};

        // nkv is a multiple of 128 for both tiles of the pair:
        // tile0: (bx+1)*128, tile1: (16-bx)*128 (causal); 2048 (dense).
        int nkv = causal ? (q0t + 128) : S;

        for (int kv0g = 0; kv0g < nkv; kv0g += 128) {
            int kv0 = kv0g + gsel * 64;
            short* Vtc = smem + (gsel * 2 + buf) * 64 * VP2;
            // ---- stage V^T (64 kv x 64 d): 2 kv x 8 d per thread ----
            {
                const short* vs0 = base + (size_t)(kv0 + vi2) * C3 + 128 + vd0;
                union { short8 v; unsigned short u[8]; } a, b;
                a.v = *(const short8*)vs0;
                b.v = *(const short8*)(vs0 + C3);
                unsigned int* vt = (unsigned int*)Vtc;
#pragma unroll
                for (int j = 0; j < 8; j++)
                    vt[((vd0 + j) * VP2 + vi2) >> 1] =
                        ((unsigned int)b.u[j] << 16) | a.u[j];
            }
            __syncthreads();

            // ---- S^T for both q-groups, shared K loads ----
            f32x4 s[2][4];
#pragma unroll
            for (int sub = 0; sub < 4; sub++) {
                const short* kb = base + (size_t)(kv0 + sub * 16 + lrow) * C3 + 64;
                short8 kf0 = *(const short8*)(kb + lq * 8);
                short8 kf1 = *(const short8*)(kb + 32 + lq * 8);
#pragma unroll
                for (int g = 0; g < 2; g++) {
                    f32x4 a = (f32x4){0.f, 0.f, 0.f, 0.f};
                    a = mfma16(kf0, qf0[g], a);
                    a = mfma16(kf1, qf1[g], a);
                    s[g][sub] = a;
                }
            }

            // ---- per-group: mask, online softmax (defer-max), pack P ----
#pragma unroll
            for (int g = 0; g < 2; g++) {
                if (causal && (kv0 + 63 > q0t + wq * 32 + g * 16)) {
#pragma unroll
                    for (int sub = 0; sub < 4; sub++) {
                        int kvg = kv0 + sub * 16 + lq * 4;
#pragma unroll
                        for (int r = 0; r < 4; r++)
                            if (kvg + r > qg[g]) s[g][sub][r] = -1e30f;
                    }
                }
                float vmax = -1e38f;
#pragma unroll
                for (int sub = 0; sub < 4; sub++) {
                    float a = fmaxf(fmaxf(s[g][sub][0], s[g][sub][1]),
                                    fmaxf(s[g][sub][2], s[g][sub][3]));
                    vmax = fmaxf(vmax, a);
                }
                vmax = fmaxf(vmax, __shfl_xor(vmax, 16, 64));
                vmax = fmaxf(vmax, __shfl_xor(vmax, 32, 64));
                float mnew = m_i[g];
                // defer-max: only rescale when some row's max grew past m+8
                if (!__all(vmax <= m_i[g] + 8.0f)) {
                    mnew = fmaxf(m_i[g], vmax);
                    float alpha = __expf(m_i[g] - mnew);
                    l_i[g] *= alpha;
#pragma unroll
                    for (int nt = 0; nt < 4; nt++)
#pragma unroll
                        for (int r = 0; r < 4; r++) acc[g][nt][r] *= alpha;
                }
                float lsum = 0.f;
                unsigned int pk[4][2];
#pragma unroll
                for (int sub = 0; sub < 4; sub++) {
                    float p0 = __expf(s[g][sub][0] - mnew);
                    float p1 = __expf(s[g][sub][1] - mnew);
                    float p2 = __expf(s[g][sub][2] - mnew);
                    float p3 = __expf(s[g][sub][3] - mnew);
                    lsum += (p0 + p1) + (p2 + p3);
                    pk[sub][0] = ((unsigned int)f2bfu(p1) << 16) | f2bfu(p0);
                    pk[sub][1] = ((unsigned int)f2bfu(p3) << 16) | f2bfu(p2);
                }
                lsum += __shfl_xor(lsum, 16, 64);
                lsum += __shfl_xor(lsum, 32, 64);
                l_i[g] += lsum;
                m_i[g] = mnew;
                // P[q=lrow][kv=sub*16+lq*4 .. +3] : 4 x ds_write_b64
                unsigned int* pt = (unsigned int*)(g ? PtB : PtA);
#pragma unroll
                for (int sub = 0; sub < 4; sub++)
                    *(uint2*)&pt[(lrow * PP + sub * 16 + lq * 4) >> 1] =
                        make_uint2(pk[sub][0], pk[sub][1]);
            }

            // ---- PV: O^T += V^T · P^T, vf shared across q-groups ----
#pragma unroll
            for (int ks = 0; ks < 2; ks++) {
                short8 pfA = *(short8*)&PtA[lrow * PP + ks * 32 + lq * 8];
                short8 pfB = *(short8*)&PtB[lrow * PP + ks * 32 + lq * 8];
#pragma unroll
                for (int nt = 0; nt < 4; nt++) {
                    short8 vf = *(short8*)&Vtc[(nt * 16 + lrow) * VP2 + ks * 32 + lq * 8];
                    acc[0][nt] = mfma16(vf, pfA, acc[0][nt]);
                    acc[1][nt] = mfma16(vf, pfB, acc[1][nt]);
                }
            }
            buf ^= 1;
        }

        // ---- merge kv-group partials (LDS exchange), then epilogue ----
        __syncthreads();                       // all PV reads of smem done
        float* ex = (float*)smem;              // 37,888 B of 73,728 B: in-bounds
        float* px = ex + (wq * 64 + lane) * 37;  // stride 37: conflict-free
        if (gsel) {
#pragma unroll
            for (int g = 0; g < 2; g++) {
                px[g * 18 + 0] = m_i[g];
                px[g * 18 + 1] = l_i[g];
#pragma unroll
                for (int nt = 0; nt < 4; nt++)
#pragma unroll
                    for (int r = 0; r < 4; r++)
                        px[g * 18 + 2 + nt * 4 + r] = acc[g][nt][r];
            }
        }
        __syncthreads();
        if (!gsel) {
#pragma unroll
            for (int g = 0; g < 2; g++) {
                float mb = px[g * 18 + 0], lb = px[g * 18 + 1];
                float mn = fmaxf(m_i[g], mb);
                float ea = __expf(m_i[g] - mn), eb = __expf(mb - mn);
                float inv = 1.f / (l_i[g] * ea + lb * eb);
                float fa = ea * inv, fb = eb * inv;
                short* ob = AO + ((size_t)bh * S + qg[g]) * 64;
#pragma unroll
                for (int nt = 0; nt < 4; nt++) {
                    const float* pb = &px[g * 18 + 2 + nt * 4];
                    float o0 = scrub(acc[g][nt][0] * fa + pb[0] * fb, 4e4f);
                    float o1 = scrub(acc[g][nt][1] * fa + pb[1] * fb, 4e4f);
                    float o2 = scrub(acc[g][nt][2] * fa + pb[2] * fb, 4e4f);
                    float o3 = scrub(acc[g][nt][3] * fa + pb[3] * fb, 4e4f);
                    unsigned int u0 = ((unsigned int)f2bfu(o1) << 16) | f2bfu(o0);
                    unsigned int u1 = ((unsigned int)f2bfu(o3) << 16) | f2bfu(o2);
                    *(uint2*)(ob + nt * 16 + lq * 4) = make_uint2(u0, u1);
                }
            }
        }
        __syncthreads();                       // exchange reads done before next stage
    }
}

// ---- launch ----
extern "C" void kernel_launch(void* const* d_in, const int* in_sizes, int n_in,
                              void* d_out, int out_size, void* d_ws, size_t ws_size,
                              hipStream_t stream) {
    char* ws = (char*)d_ws;
    int*   flag  = (int*)ws;
    short* bq_bf = (short*)(ws + 65536);
    short* bo_bf = (short*)(ws + 131072);
    short* WqkvT = (short*)(ws + (1ull << 20));
    short* WoutT = (short*)(ws + 7ull * (1ull << 20));
    short* xbfAO = (short*)(ws + 9ull * (1ull << 20));   // x_bf, later AO
    short* QKVc  = (short*)(ws + 25ull * (1ull << 20));

    detect_dtype<<<1, 256, 0, stream>>>((const unsigned short*)d_in[0], flag);

    if (ws_size < 73ull * 1048576) {
        fill_sentinel<<<(8388608 + 255) / 256, 256, 0, stream>>>(d_out, 8388608, flag);
        return;
    }

    conv_bias<<<12, 256, 0, stream>>>(d_in[2], bq_bf, 3072, flag);
    conv_bias<<<4, 256, 0, stream>>>(d_in[4], bo_bf, 1024, flag);
    transpose_poly<<<dim3(96, 32), 256, 0, stream>>>(d_in[1], WqkvT, 1024, 3072, flag);
    transpose_poly<<<dim3(32, 32), 256, 0, stream>>>(d_in[3], WoutT, 1024, 1024, flag);
    conv_x<<<8192, 256, 0, stream>>>(d_in[0], xbfAO, 8388608, flag);

    gemm_bt<<<dim3(24, 64), 256, 0, stream>>>(xbfAO, WqkvT, bq_bf, QKVc,
                                              3072, 1024, flag, 0, 8e4f);
    attn_kernel<<<dim3(8, 64), 512, 0, stream>>>(QKVc, xbfAO, (const int*)d_in[5]);
    gemm_bt<<<dim3(8, 64), 256, 0, stream>>>(xbfAO, WoutT, bo_bf, d_out,
                                             1024, 1024, flag, 1, 2e4f);
}

// Round 3
// 354.466 us; speedup vs baseline: 1.0958x; 1.0958x over previous
//
#include <hip/hip_runtime.h>
#include <hip/hip_bf16.h>

typedef __attribute__((ext_vector_type(8))) short short8;
typedef __attribute__((ext_vector_type(4))) float f32x4;

__device__ inline f32x4 mfma16(short8 a, short8 b, f32x4 c) {
    return __builtin_amdgcn_mfma_f32_16x16x32_bf16(a, b, c, 0, 0, 0);
}
__device__ inline short f2bf(float x) {
    __hip_bfloat16 h = __float2bfloat16(x);
    return *reinterpret_cast<short*>(&h);
}
__device__ inline unsigned short f2bfu(float x) {
    __hip_bfloat16 h = __float2bfloat16(x);
    return *reinterpret_cast<unsigned short*>(&h);
}
__device__ inline float bf2f(short u) {
    __hip_bfloat16 h = *reinterpret_cast<__hip_bfloat16*>(&u);
    return __bfloat162float(h);
}
__device__ inline float scrub(float v, float s) {
    return (fabsf(v) < 1e30f) ? v : s;
}
__device__ inline short8 scaleq(short8 v) {   // fold 1/sqrt(hd)=0.125 into Q (exact in bf16)
    short8 r;
#pragma unroll
    for (int j = 0; j < 8; j++) r[j] = f2bf(bf2f(v[j]) * 0.125f);
    return r;
}

// ---- dtype detection ----
__global__ void detect_dtype(const unsigned short* __restrict__ x, int* flag) {
    __shared__ int cnt;
    if (threadIdx.x == 0) cnt = 0;
    __syncthreads();
    int c = 0;
    for (int i = threadIdx.x; i < 1024; i += 256) {
        unsigned short u = x[i];
        int e = (u >> 7) & 0xFF;
        if ((u & 0x7FFF) == 0 || (e >= 110 && e <= 143)) c++;
    }
    atomicAdd(&cnt, c);
    __syncthreads();
    if (threadIdx.x == 0) flag[0] = (cnt < 819) ? 1 : 0;
}

__global__ void conv_bias(const void* __restrict__ in, short* __restrict__ out,
                          int n, const int* __restrict__ flag) {
    int i = blockIdx.x * 256 + threadIdx.x;
    if (i >= n) return;
    out[i] = (*flag) ? f2bf(((const float*)in)[i]) : ((const short*)in)[i];
}

__global__ __launch_bounds__(256) void conv_x(const void* __restrict__ in,
                                              short* __restrict__ out, int n,
                                              const int* __restrict__ flag) {
    int i = (blockIdx.x * 256 + threadIdx.x) * 4;
    if (i >= n) return;
    if (*flag) {
        float4 f = *(const float4*)((const float*)in + i);
        unsigned int u0 = ((unsigned int)f2bfu(f.y) << 16) | f2bfu(f.x);
        unsigned int u1 = ((unsigned int)f2bfu(f.w) << 16) | f2bfu(f.z);
        *(uint2*)(out + i) = make_uint2(u0, u1);
    } else {
        *(uint2*)(out + i) = *(const uint2*)((const short*)in + i);
    }
}

__global__ void fill_sentinel(void* out, int n, const int* __restrict__ flag) {
    int i = blockIdx.x * 256 + threadIdx.x;
    if (i >= n) return;
    if (*flag) ((float*)out)[i] = 3e5f; else ((short*)out)[i] = f2bf(3e5f);
}

// ---- transpose (poly input) ----
__global__ __launch_bounds__(256) void transpose_poly(const void* __restrict__ in,
                                                      short* __restrict__ out,
                                                      int R, int C,
                                                      const int* __restrict__ flag) {
    __shared__ short tile[32][33];
    const bool f32 = (*flag) != 0;
    int tx = threadIdx.x & 31, ty = threadIdx.x >> 5;
    int r0 = blockIdx.y * 32, c0 = blockIdx.x * 32;
#pragma unroll
    for (int i = 0; i < 4; i++) {
        size_t off = (size_t)(r0 + ty + i * 8) * C + c0 + tx;
        tile[ty + i * 8][tx] = f32 ? f2bf(((const float*)in)[off]) : ((const short*)in)[off];
    }
    __syncthreads();
#pragma unroll
    for (int i = 0; i < 4; i++)
        out[(size_t)(c0 + ty + i * 8) * R + r0 + tx] = tile[tx][ty + i * 8];
}

// ---- GEMM (unchanged) ----
#define LDK 72

__global__ __launch_bounds__(256) void gemm_bt(const short* __restrict__ A,
                                               const short* __restrict__ Bt,
                                               const short* __restrict__ bias,
                                               void* __restrict__ Cv,
                                               int N, int K,
                                               const int* __restrict__ flag,
                                               int c_poly, float sent) {
    alignas(16) __shared__ short As[128 * LDK];
    alignas(16) __shared__ short Bs[128 * LDK];
    const bool cf32 = c_poly && (*flag);
    int tid = threadIdx.x;
    int wave = tid >> 6, lane = tid & 63;
    int lrow = lane & 15, lq = lane >> 4;
    int wm = (wave >> 1) * 64, wn = (wave & 1) * 64;
    int m0 = blockIdx.y * 128, n0 = blockIdx.x * 128;

    f32x4 acc[4][4];
#pragma unroll
    for (int i = 0; i < 4; i++)
#pragma unroll
        for (int j = 0; j < 4; j++) acc[i][j] = (f32x4){0.f, 0.f, 0.f, 0.f};

    int srow = tid >> 3;
    int scol = (tid & 7) * 8;

    for (int kb = 0; kb < K; kb += 64) {
#pragma unroll
        for (int p = 0; p < 4; p++) {
            int row = p * 32 + srow;
            *(short8*)&As[row * LDK + scol] =
                *(const short8*)&A[(size_t)(m0 + row) * K + kb + scol];
            *(short8*)&Bs[row * LDK + scol] =
                *(const short8*)&Bt[(size_t)(n0 + row) * K + kb + scol];
        }
        __syncthreads();
#pragma unroll
        for (int ks = 0; ks < 2; ks++) {
            short8 af[4], bf[4];
#pragma unroll
            for (int i = 0; i < 4; i++)
                af[i] = *(short8*)&As[(wm + i * 16 + lrow) * LDK + ks * 32 + lq * 8];
#pragma unroll
            for (int i = 0; i < 4; i++)
                bf[i] = *(short8*)&Bs[(wn + i * 16 + lrow) * LDK + ks * 32 + lq * 8];
#pragma unroll
            for (int i = 0; i < 4; i++)
#pragma unroll
                for (int j = 0; j < 4; j++)
                    acc[i][j] = mfma16(af[i], bf[j], acc[i][j]);
        }
        __syncthreads();
    }

    const __hip_bfloat16* bias16 = (const __hip_bfloat16*)bias;
#pragma unroll
    for (int j = 0; j < 4; j++) {
        int col = n0 + wn + j * 16 + lrow;
        float bv = __bfloat162float(bias16[col]);
#pragma unroll
        for (int i = 0; i < 4; i++) {
            int rbase = m0 + wm + i * 16 + lq * 4;
#pragma unroll
            for (int r = 0; r < 4; r++) {
                float val = scrub(acc[i][j][r] + bv, sent);
                size_t off = (size_t)(rbase + r) * N + col;
                if (cf32) ((float*)Cv)[off] = val; else ((short*)Cv)[off] = f2bf(val);
            }
        }
    }
}

// ---- flash attention, S^T formulation, 128 q / block, kv-split x2 ----------
// Block = 512 threads (8 waves). Waves 0-3 (kv-group 0) and 4-7 (kv-group 1)
// own the SAME 128 q rows but alternate 64-kv iterations: group g processes
// kv0 = kv0g + g*64, kv0g += 128. Both tile kv-counts are multiples of 128 ->
// identical trip counts, uniform barriers. Private (m,l,acc) per group; LDS
// merge at tile end. Doubles waves/CU (8 -> 16) vs the 256-thread version.
// __launch_bounds__(512, 2): round-2's (512, 4) made the allocator squeeze to
// 64 VGPR -> inner-loop scratch spills (WRITE_SIZE 16->47 MB, FETCH 147->289
// MB, VALUBusy halved). Per-thread live state needs ~130-150 regs; (512,2)
// caps at 1024 so the allocator is unconstrained. Occupancy stays LDS-capped
// at 2 blocks/CU = 16 waves/CU regardless.
#define VP2 72
#define PP 72
#define VT_ELEMS (2 * 2 * 64 * VP2)   // 18432 shorts = 36864 B
#define PT_ELEMS (8 * 2 * 16 * PP)    // 18432 shorts = 36864 B

__global__ __launch_bounds__(512, 2) void attn_kernel(const short* __restrict__ QKV,
                                                      short* __restrict__ AO,
                                                      const int* __restrict__ maskp) {
    constexpr int S = 2048, C3 = 3072;
    alignas(16) __shared__ short smem[VT_ELEMS + PT_ELEMS];

    int tid = threadIdx.x;
    int wave = tid >> 6, lane = tid & 63;
    int wq = wave & 3, gsel = wave >> 2;
    int lrow = lane & 15, lq = lane >> 4;
    int bh = blockIdx.y;
    const bool causal = (*maskp) != 0;
    const short* base = QKV + (size_t)(bh >> 4) * S * C3 + (bh & 15) * 192;

    int t8 = tid & 255;               // index within kv-group's 256 threads
    int vi2 = (t8 & 31) * 2;          // kv pair base for V staging
    int vd0 = (t8 >> 5) * 8;          // 8 d per thread

    short* PtA = smem + VT_ELEMS + (wave * 2 + 0) * 16 * PP;
    short* PtB = smem + VT_ELEMS + (wave * 2 + 1) * 16 * PP;

    int buf = 0;
    for (int tile = 0; tile < 2; tile++) {
        int q0t = (tile == 0) ? blockIdx.x * 128 : 1920 - blockIdx.x * 128;

        int qg[2];
        short8 qf0[2], qf1[2];
#pragma unroll
        for (int g = 0; g < 2; g++) {
            qg[g] = q0t + wq * 32 + g * 16 + lrow;
            qf0[g] = scaleq(*(const short8*)(base + (size_t)qg[g] * C3 + lq * 8));
            qf1[g] = scaleq(*(const short8*)(base + (size_t)qg[g] * C3 + 32 + lq * 8));
        }

        float m_i[2] = {-1e38f, -1e38f}, l_i[2] = {0.f, 0.f};
        f32x4 acc[2][4];
#pragma unroll
        for (int g = 0; g < 2; g++)
#pragma unroll
            for (int nt = 0; nt < 4; nt++) acc[g][nt] = (f32x4){0.f, 0.f, 0.f, 0.f};

        // nkv is a multiple of 128 for both tiles of the pair:
        // tile0: (bx+1)*128, tile1: (16-bx)*128 (causal); 2048 (dense).
        int nkv = causal ? (q0t + 128) : S;

        for (int kv0g = 0; kv0g < nkv; kv0g += 128) {
            int kv0 = kv0g + gsel * 64;
            short* Vtc = smem + (gsel * 2 + buf) * 64 * VP2;
            // ---- stage V^T (64 kv x 64 d): 2 kv x 8 d per thread ----
            {
                const short* vs0 = base + (size_t)(kv0 + vi2) * C3 + 128 + vd0;
                union { short8 v; unsigned short u[8]; } a, b;
                a.v = *(const short8*)vs0;
                b.v = *(const short8*)(vs0 + C3);
                unsigned int* vt = (unsigned int*)Vtc;
#pragma unroll
                for (int j = 0; j < 8; j++)
                    vt[((vd0 + j) * VP2 + vi2) >> 1] =
                        ((unsigned int)b.u[j] << 16) | a.u[j];
            }
            __syncthreads();

            // ---- S^T for both q-groups, shared K loads ----
            f32x4 s[2][4];
#pragma unroll
            for (int sub = 0; sub < 4; sub++) {
                const short* kb = base + (size_t)(kv0 + sub * 16 + lrow) * C3 + 64;
                short8 kf0 = *(const short8*)(kb + lq * 8);
                short8 kf1 = *(const short8*)(kb + 32 + lq * 8);
#pragma unroll
                for (int g = 0; g < 2; g++) {
                    f32x4 a = (f32x4){0.f, 0.f, 0.f, 0.f};
                    a = mfma16(kf0, qf0[g], a);
                    a = mfma16(kf1, qf1[g], a);
                    s[g][sub] = a;
                }
            }

            // ---- per-group: mask, online softmax (defer-max), pack P ----
#pragma unroll
            for (int g = 0; g < 2; g++) {
                if (causal && (kv0 + 63 > q0t + wq * 32 + g * 16)) {
#pragma unroll
                    for (int sub = 0; sub < 4; sub++) {
                        int kvg = kv0 + sub * 16 + lq * 4;
#pragma unroll
                        for (int r = 0; r < 4; r++)
                            if (kvg + r > qg[g]) s[g][sub][r] = -1e30f;
                    }
                }
                float vmax = -1e38f;
#pragma unroll
                for (int sub = 0; sub < 4; sub++) {
                    float a = fmaxf(fmaxf(s[g][sub][0], s[g][sub][1]),
                                    fmaxf(s[g][sub][2], s[g][sub][3]));
                    vmax = fmaxf(vmax, a);
                }
                vmax = fmaxf(vmax, __shfl_xor(vmax, 16, 64));
                vmax = fmaxf(vmax, __shfl_xor(vmax, 32, 64));
                float mnew = m_i[g];
                // defer-max: only rescale when some row's max grew past m+8
                if (!__all(vmax <= m_i[g] + 8.0f)) {
                    mnew = fmaxf(m_i[g], vmax);
                    float alpha = __expf(m_i[g] - mnew);
                    l_i[g] *= alpha;
#pragma unroll
                    for (int nt = 0; nt < 4; nt++)
#pragma unroll
                        for (int r = 0; r < 4; r++) acc[g][nt][r] *= alpha;
                }
                float lsum = 0.f;
                unsigned int pk[4][2];
#pragma unroll
                for (int sub = 0; sub < 4; sub++) {
                    float p0 = __expf(s[g][sub][0] - mnew);
                    float p1 = __expf(s[g][sub][1] - mnew);
                    float p2 = __expf(s[g][sub][2] - mnew);
                    float p3 = __expf(s[g][sub][3] - mnew);
                    lsum += (p0 + p1) + (p2 + p3);
                    pk[sub][0] = ((unsigned int)f2bfu(p1) << 16) | f2bfu(p0);
                    pk[sub][1] = ((unsigned int)f2bfu(p3) << 16) | f2bfu(p2);
                }
                lsum += __shfl_xor(lsum, 16, 64);
                lsum += __shfl_xor(lsum, 32, 64);
                l_i[g] += lsum;
                m_i[g] = mnew;
                // P[q=lrow][kv=sub*16+lq*4 .. +3] : 4 x ds_write_b64
                unsigned int* pt = (unsigned int*)(g ? PtB : PtA);
#pragma unroll
                for (int sub = 0; sub < 4; sub++)
                    *(uint2*)&pt[(lrow * PP + sub * 16 + lq * 4) >> 1] =
                        make_uint2(pk[sub][0], pk[sub][1]);
            }

            // ---- PV: O^T += V^T · P^T, vf shared across q-groups ----
#pragma unroll
            for (int ks = 0; ks < 2; ks++) {
                short8 pfA = *(short8*)&PtA[lrow * PP + ks * 32 + lq * 8];
                short8 pfB = *(short8*)&PtB[lrow * PP + ks * 32 + lq * 8];
#pragma unroll
                for (int nt = 0; nt < 4; nt++) {
                    short8 vf = *(short8*)&Vtc[(nt * 16 + lrow) * VP2 + ks * 32 + lq * 8];
                    acc[0][nt] = mfma16(vf, pfA, acc[0][nt]);
                    acc[1][nt] = mfma16(vf, pfB, acc[1][nt]);
                }
            }
            buf ^= 1;
        }

        // ---- merge kv-group partials (LDS exchange), then epilogue ----
        __syncthreads();                       // all PV reads of smem done
        float* ex = (float*)smem;              // 37,888 B of 73,728 B: in-bounds
        float* px = ex + (wq * 64 + lane) * 37;  // stride 37: conflict-free
        if (gsel) {
#pragma unroll
            for (int g = 0; g < 2; g++) {
                px[g * 18 + 0] = m_i[g];
                px[g * 18 + 1] = l_i[g];
#pragma unroll
                for (int nt = 0; nt < 4; nt++)
#pragma unroll
                    for (int r = 0; r < 4; r++)
                        px[g * 18 + 2 + nt * 4 + r] = acc[g][nt][r];
            }
        }
        __syncthreads();
        if (!gsel) {
#pragma unroll
            for (int g = 0; g < 2; g++) {
                float mb = px[g * 18 + 0], lb = px[g * 18 + 1];
                float mn = fmaxf(m_i[g], mb);
                float ea = __expf(m_i[g] - mn), eb = __expf(mb - mn);
                float inv = 1.f / (l_i[g] * ea + lb * eb);
                float fa = ea * inv, fb = eb * inv;
                short* ob = AO + ((size_t)bh * S + qg[g]) * 64;
#pragma unroll
                for (int nt = 0; nt < 4; nt++) {
                    const float* pb = &px[g * 18 + 2 + nt * 4];
                    float o0 = scrub(acc[g][nt][0] * fa + pb[0] * fb, 4e4f);
                    float o1 = scrub(acc[g][nt][1] * fa + pb[1] * fb, 4e4f);
                    float o2 = scrub(acc[g][nt][2] * fa + pb[2] * fb, 4e4f);
                    float o3 = scrub(acc[g][nt][3] * fa + pb[3] * fb, 4e4f);
                    unsigned int u0 = ((unsigned int)f2bfu(o1) << 16) | f2bfu(o0);
                    unsigned int u1 = ((unsigned int)f2bfu(o3) << 16) | f2bfu(o2);
                    *(uint2*)(ob + nt * 16 + lq * 4) = make_uint2(u0, u1);
                }
            }
        }
        __syncthreads();                       // exchange reads done before next stage
    }
}

// ---- launch ----
extern "C" void kernel_launch(void* const* d_in, const int* in_sizes, int n_in,
                              void* d_out, int out_size, void* d_ws, size_t ws_size,
                              hipStream_t stream) {
    char* ws = (char*)d_ws;
    int*   flag  = (int*)ws;
    short* bq_bf = (short*)(ws + 65536);
    short* bo_bf = (short*)(ws + 131072);
    short* WqkvT = (short*)(ws + (1ull << 20));
    short* WoutT = (short*)(ws + 7ull * (1ull << 20));
    short* xbfAO = (short*)(ws + 9ull * (1ull << 20));   // x_bf, later AO
    short* QKVc  = (short*)(ws + 25ull * (1ull << 20));

    detect_dtype<<<1, 256, 0, stream>>>((const unsigned short*)d_in[0], flag);

    if (ws_size < 73ull * 1048576) {
        fill_sentinel<<<(8388608 + 255) / 256, 256, 0, stream>>>(d_out, 8388608, flag);
        return;
    }

    conv_bias<<<12, 256, 0, stream>>>(d_in[2], bq_bf, 3072, flag);
    conv_bias<<<4, 256, 0, stream>>>(d_in[4], bo_bf, 1024, flag);
    transpose_poly<<<dim3(96, 32), 256, 0, stream>>>(d_in[1], WqkvT, 1024, 3072, flag);
    transpose_poly<<<dim3(32, 32), 256, 0, stream>>>(d_in[3], WoutT, 1024, 1024, flag);
    conv_x<<<8192, 256, 0, stream>>>(d_in[0], xbfAO, 8388608, flag);

    gemm_bt<<<dim3(24, 64), 256, 0, stream>>>(xbfAO, WqkvT, bq_bf, QKVc,
                                              3072, 1024, flag, 0, 8e4f);
    attn_kernel<<<dim3(8, 64), 512, 0, stream>>>(QKVc, xbfAO, (const int*)d_in[5]);
    gemm_bt<<<dim3(8, 64), 256, 0, stream>>>(xbfAO, WoutT, bo_bf, d_out,
                                             1024, 1024, flag, 1, 2e4f);
}